// Round 7
// baseline (526.781 us; speedup 1.0000x reference)
//
#include <hip/hip_runtime.h>
#include <hip/hip_bf16.h>

// Problem constants
#define B_    32
#define C_    256
#define HW_   3136   // 56*56
#define OC_   256
#define M_    8
#define KPB_  589824 // per-sample wl shorts: 72 kblocks * 8192

typedef short v8s __attribute__((ext_vector_type(8)));   // 8 x bf16 (4 VGPRs)
typedef float f32x4 __attribute__((ext_vector_type(4)));

union bf8pack { v8s v; __hip_bfloat16 h[8]; };

__device__ __forceinline__ void gll16(const short* src, short* dst) {
    __builtin_amdgcn_global_load_lds((const __attribute__((address_space(1))) void*)src,
                                     (__attribute__((address_space(3))) void*)dst, 16, 0, 0);
}

// ---------------------------------------------------------------------------
// 0) zero the gap accumulator (ws is poisoned 0xAA before every launch)
__global__ void zero_gap_kernel(float* __restrict__ gap) {
    gap[blockIdx.x * 256 + threadIdx.x] = 0.f;
}

// ---------------------------------------------------------------------------
// 1) x (f32, BCHW) -> xg (bf16, [b][ib=8][p][32] channel-blocked), fused GAP.
__global__ __launch_bounds__(256) void xcast_kernel(const float* __restrict__ x,
                                                    short* __restrict__ xg,
                                                    float* __restrict__ gap) {
    __shared__ __hip_bfloat16 tile[64][65];   // [channel][pixel], +1 pad
    int b = blockIdx.z, ct = blockIdx.y, pt = blockIdx.x;
    int p0 = pt*64, c0 = ct*64;
    int tp = threadIdx.x & 63, tc = threadIdx.x >> 6;
    const float* xb = x + ((size_t)b*C_ + c0) * HW_ + p0;
    #pragma unroll
    for (int j = 0; j < 16; ++j) {
        int cl = tc + j*4;
        float v = xb[(size_t)cl*HW_ + tp];
        tile[cl][tp] = __float2bfloat16(v);
        float s = v;
        #pragma unroll
        for (int off = 32; off; off >>= 1) s += __shfl_xor(s, off, 64);
        if (tp == 0) atomicAdd(&gap[b*C_ + c0 + cl], s);
    }
    __syncthreads();
    #pragma unroll
    for (int it = 0; it < 2; ++it) {
        int idx = it*256 + threadIdx.x;
        int px = idx >> 3, ck = idx & 7;
        bf8pack pk;
        #pragma unroll
        for (int j = 0; j < 8; ++j) pk.h[j] = tile[ck*8 + j][px];
        int c = c0 + ck*8;
        size_t dst = (((size_t)b*8 + (c >> 5))*HW_ + p0 + px)*32 + (c & 31);
        *(v8s*)(xg + dst) = pk.v;
    }
}

// ---------------------------------------------------------------------------
// 2) Gate softmax + combined bias, fused. One wave per sample. gap holds SUMS.
__global__ void alpha_kernel(const float* __restrict__ gap,
                             const float* __restrict__ gate_w,
                             const float* __restrict__ gate_b,
                             const float* __restrict__ bias,
                             float* __restrict__ alpha,
                             float* __restrict__ biasc) {
    int b = blockIdx.x, lane = threadIdx.x;
    const float inv = 1.0f / HW_;
    float g0 = gap[b*C_ + lane]*inv,       g1 = gap[b*C_ + 64 + lane]*inv;
    float g2 = gap[b*C_ + 128 + lane]*inv, g3 = gap[b*C_ + 192 + lane]*inv;
    float logit[M_];
    #pragma unroll
    for (int m = 0; m < M_; ++m) {
        const float* w = gate_w + m*C_;
        float s = g0*w[lane] + g1*w[64+lane] + g2*w[128+lane] + g3*w[192+lane];
        for (int off = 32; off; off >>= 1) s += __shfl_xor(s, off, 64);
        logit[m] = s + gate_b[m];
    }
    float mx = logit[0];
    #pragma unroll
    for (int m = 1; m < M_; ++m) mx = fmaxf(mx, logit[m]);
    float den = 0.f, e[M_];
    #pragma unroll
    for (int m = 0; m < M_; ++m) { e[m] = __expf(logit[m] - mx); den += e[m]; }
    float am[M_];
    #pragma unroll
    for (int m = 0; m < M_; ++m) am[m] = e[m] / den;
    if (lane < M_) alpha[b*M_ + lane] = am[lane];
    #pragma unroll
    for (int r = 0; r < 4; ++r) {
        int o = r*64 + lane;
        float s = 0.f;
        #pragma unroll
        for (int m = 0; m < M_; ++m) s += am[m] * bias[m*OC_ + o];
        biasc[b*OC_ + o] = s;
    }
}

// ---------------------------------------------------------------------------
// 3) Combine expert kernels: wl[b][ib(8)][tap(9)][o(256)][i_in(32)] bf16.
//    NEW: grid.y=8 splits the sample loop (4 b each) -> 2304 blocks (9/CU)
//    so the 64 stride-9 scalar gathers have TLP to hide latency (round-5
//    lesson: ~1 block/CU is latency-starved). Weight re-reads x8 are
//    L2/L3-absorbed (9.4 MB). Per-b arithmetic identical (bit-exact).
__global__ __launch_bounds__(256) void combine_kernel(const float* __restrict__ weight,
                                                      const float* __restrict__ alpha,
                                                      short* __restrict__ wl) {
    __shared__ float as[B_*M_];
    as[threadIdx.x] = alpha[threadIdx.x];
    __syncthreads();
    int gc  = blockIdx.x*256 + threadIdx.x;   // [0, 73728)
    int i8  = gc & 3;
    int o   = (gc >> 2) & 255;
    int t2  = gc >> 10;
    int tap = t2 % 9;
    int ib  = t2 / 9;
    int base = o*2304 + (ib*32 + i8*8)*9 + tap;   // + j*9
    float wv[M_][8];
    #pragma unroll
    for (int m = 0; m < M_; ++m)
        #pragma unroll
        for (int j = 0; j < 8; ++j)
            wv[m][j] = weight[(size_t)m*589824 + base + j*9];
    int b0 = blockIdx.y * 4;
    #pragma unroll
    for (int bi = 0; bi < 4; ++bi) {
        int b = b0 + bi;
        bf8pack pk;
        #pragma unroll
        for (int j = 0; j < 8; ++j) {
            float s = 0.f;
            #pragma unroll
            for (int m = 0; m < M_; ++m) s += as[b*M_+m] * wv[m][j];
            pk.h[j] = __float2bfloat16(s);
        }
        *(v8s*)(wl + (size_t)b*KPB_ + (size_t)gc*8) = pk.v;
    }
}

// ---------------------------------------------------------------------------
// 4) Implicit-GEMM conv, MFMA bf16 16x16x32.
//    B-FRAGMENT REGISTER DOUBLE-BUFFER on top of round-6's barrier-light loop.
//    Block = 128o x 224px, 4 waves; wave = 64o x 112px, acc[4][7] = 112.
//    Round-6 counters: MFMA 1086 + LDS ~750 + VALU ~690 cyc/tap SERIALIZED
//    (MfmaUtil 37.6, VALUBusy 27). Fixes:
//      (a) B frags for tap t+1 are ds_read into the ALTERNATE named reg
//          buffer while tap t's MFMAs run -> LDS latency off critical path.
//      (b) pad-mask as PREDICATED ADDRESS into a zeroed LDS slot (7 cndmask
//          /tap vs 112 operand-select cndmask) -> VALU off critical path.
//      (c) tap8 does NOT prefetch next-ib tap0 (would race stageB); tap0
//          frags load right after the per-ib barrier (~130 cyc bubble/ib).
//    A (wl): global->reg, 3 slots, distance-2 (slot = k%3 == tap%3).
//    Registers: 112 acc + 56 braw + 48 areg + ~30 misc = 246 <= 256 @ (256,2).
//    LDS: B dbuf 2x24KB + 16B zero slot -> 2 blocks/CU, 8 waves/CU.
__global__ __launch_bounds__(256, 2) void conv_kernel(const short* __restrict__ xg,
                                                      const short* __restrict__ wl,
                                                      const float* __restrict__ biasc,
                                                      float* __restrict__ out) {
    __shared__ short smem[24584];  // B0@0, B1@12288, zero@24576 (shorts)
    const int ZOFF = 24576;

    // T1: XCD swizzle, 896 = 8*112 bijective. Consecutive swz share sample b.
    const int wg  = blockIdx.x;
    const int swz = (wg & 7) * 112 + (wg >> 3);
    const int b   = swz / 28;
    const int rm  = swz - b * 28;
    const int ot  = rm / 14;
    const int pt  = rm - ot * 14;

    const int tid = threadIdx.x;
    const int wave = tid >> 6, lane = tid & 63, q = lane >> 4, ln = lane & 15;
    const int o_half = wave >> 1, p_half = wave & 1;
    const int P0 = pt * 224;

    const int DOFF[9] = {-57,-56,-55,-1,0,1,55,56,57};

    unsigned vmask[7];
    #pragma unroll
    for (int c = 0; c < 7; ++c) {
        int p = P0 + p_half*112 + c*16 + ln;     // always < 3136 (14*224 exact)
        int h = p/56, w = p%56;
        unsigned m = 0;
        #pragma unroll
        for (int tap = 0; tap < 9; ++tap) {
            int h2 = h + tap/3 - 1, w2 = w + tap%3 - 1;
            if ((unsigned)h2 < 56u && (unsigned)w2 < 56u) m |= (1u << tap);
        }
        vmask[c] = m;
    }

    const short* wbase = wl + (size_t)b*KPB_ + ((ot*128 + o_half*64 + ln)*32 + q*8);
    const short* xbase = xg + (size_t)(b*8)*HW_*32;

    auto stageB = [&](int ib, int buf) {   // 24KB halo [P0-64, P0+320), 6 gll16
        const short* src = xbase + ((long)ib*HW_ + P0 - 64)*32 + tid*8;
        short* dst = &smem[buf*12288 + tid*8];
        #pragma unroll
        for (int r = 0; r < 6; ++r) gll16(src + r*2048, dst + r*2048);
    };

    v8s areg[3][4];                        // 3 slots, distance-2 prefetch
    auto loadA = [&](int kidx, v8s (&dst)[4]) {
        const short* src = wbase + (size_t)kidx*8192;
        #pragma unroll
        for (int r = 0; r < 4; ++r) dst[r] = *(const v8s*)(src + r*512);
    };

    const int bcol0 = (64 + p_half*112 + ln)*32 + q*8;
    // predicated-address B fragment load: masked lanes read the zero slot
    auto loadBfrags = [&](int tap, int ibpar, v8s (&dst)[7]) {
        const int base = ibpar*12288 + bcol0 + DOFF[tap]*32;
        #pragma unroll
        for (int c = 0; c < 7; ++c) {
            int off = ((vmask[c] >> tap) & 1) ? (base + c*512) : ZOFF;
            dst[c] = *(const v8s*)&smem[off];
        }
    };

    f32x4 acc[4][7];
    #pragma unroll
    for (int r = 0; r < 4; ++r)
        #pragma unroll
        for (int c = 0; c < 7; ++c) acc[r][c] = (f32x4){0.f,0.f,0.f,0.f};

    if (tid == 0) { *(v8s*)&smem[ZOFF] = (v8s){}; }   // zero slot

    // Prologue: B(0) + A k=0 (slot 0), k=1 (slot 1).
    stageB(0, 0);
    loadA(0, areg[0]);
    loadA(1, areg[1]);

    v8s brA[7], brB[7];                    // named B reg buffers (rule #20)

    for (int io = 0; io < 2; ++io) {
        #pragma unroll
        for (int i4 = 0; i4 < 4; ++i4) {
            const int ib = io*4 + i4;      // ib&1 == i4&1
            // One barrier per ib: publishes B(ib), frees the other buffer.
            __syncthreads();
            if (ib < 7) stageB(ib + 1, (i4 + 1) & 1);
            loadBfrags(0, i4 & 1, brA);    // tap-0 frags (small bubble)

            #pragma unroll
            for (int tap = 0; tap < 9; ++tap) {
                const int k = ib*9 + tap;  // k%3 == tap%3
                // prefetch next tap's B frags into the other reg buffer
                if (tap < 8) {
                    if (tap & 1) loadBfrags(tap + 1, i4 & 1, brA);
                    else         loadBfrags(tap + 1, i4 & 1, brB);
                }
                if (k + 2 < 72) loadA(k + 2, areg[(tap + 2) % 3]);

                const v8s* A  = areg[tap % 3];
                const v8s* Bf = (tap & 1) ? brB : brA;
                #pragma unroll
                for (int c = 0; c < 7; ++c) {
                    #pragma unroll
                    for (int r = 0; r < 4; ++r)
                        acc[r][c] = __builtin_amdgcn_mfma_f32_16x16x32_bf16(A[r], Bf[c], acc[r][c], 0, 0, 0);
                }
            }
        }
    }

    // Epilogue: D col=lane&15 (px), row=q*4+reg (o). Exact tiling, no checks.
    const int o0 = ot*128 + o_half*64 + q*4;
    #pragma unroll
    for (int c = 0; c < 7; ++c) {
        int p = P0 + p_half*112 + c*16 + ln;
        float* op = out + (size_t)b * OC_ * HW_ + p;
        #pragma unroll
        for (int r = 0; r < 4; ++r) {
            #pragma unroll
            for (int reg = 0; reg < 4; ++reg) {
                int o = o0 + r*16 + reg;
                op[(size_t)o * HW_] = acc[r][c][reg] + biasc[b*OC_ + o];
            }
        }
    }
}

// ---------------------------------------------------------------------------
extern "C" void kernel_launch(void* const* d_in, const int* in_sizes, int n_in,
                              void* d_out, int out_size, void* d_ws, size_t ws_size,
                              hipStream_t stream) {
    const float* x      = (const float*)d_in[0];
    const float* weight = (const float*)d_in[1];
    const float* bias   = (const float*)d_in[2];
    const float* gate_w = (const float*)d_in[3];
    const float* gate_b = (const float*)d_in[4];
    float* out = (float*)d_out;

    // Workspace layout (bytes):
    //   gap   @ 0       : 32,768
    //   biasc @ 32768   : 32,768
    //   alpha @ 65536   : 1,024
    //   (pad — absorbs conv's B-halo negative overrun, up to -4 KB at P0=0)
    //   xg    @ 131072  : 32*8*3136*32*2 = 51,380,224
    //   wl    @ 51,511,296 : 32*589824*2 = 37,748,736 (absorbs B-halo tail overrun)
    char* ws = (char*)d_ws;
    float* gap   = (float*)(ws);
    float* biasc = (float*)(ws + 32768);
    float* alpha = (float*)(ws + 65536);
    short* xg    = (short*)(ws + 131072);
    short* wl    = (short*)(ws + 51511296);

    zero_gap_kernel<<<32, 256, 0, stream>>>(gap);
    xcast_kernel   <<<dim3(49, 4, 32), 256, 0, stream>>>(x, xg, gap);
    alpha_kernel   <<<32,  64, 0, stream>>>(gap, gate_w, gate_b, bias, alpha, biasc);
    combine_kernel <<<dim3(288, 8), 256, 0, stream>>>(weight, alpha, wl);
    conv_kernel    <<<896, 256, 0, stream>>>(xg, wl, biasc, out);
}

// Round 8
// 438.900 us; speedup vs baseline: 1.2002x; 1.2002x over previous
//
#include <hip/hip_runtime.h>
#include <hip/hip_bf16.h>

// Problem constants
#define B_    32
#define C_    256
#define HW_   3136   // 56*56
#define OC_   256
#define M_    8
#define KPB_  589824 // per-sample wl shorts: 72 kblocks * 8192

typedef short v8s __attribute__((ext_vector_type(8)));   // 8 x bf16 (4 VGPRs)
typedef float f32x4 __attribute__((ext_vector_type(4)));

union bf8pack { v8s v; __hip_bfloat16 h[8]; };

__device__ __forceinline__ void gll16(const short* src, short* dst) {
    __builtin_amdgcn_global_load_lds((const __attribute__((address_space(1))) void*)src,
                                     (__attribute__((address_space(3))) void*)dst, 16, 0, 0);
}

// ---------------------------------------------------------------------------
// 0) zero the gap accumulator (ws is poisoned 0xAA before every launch)
__global__ void zero_gap_kernel(float* __restrict__ gap) {
    gap[blockIdx.x * 256 + threadIdx.x] = 0.f;
}

// ---------------------------------------------------------------------------
// 1) x (f32, BCHW) -> xg (bf16, [b][ib=8][p][32] channel-blocked), fused GAP.
__global__ __launch_bounds__(256) void xcast_kernel(const float* __restrict__ x,
                                                    short* __restrict__ xg,
                                                    float* __restrict__ gap) {
    __shared__ __hip_bfloat16 tile[64][65];   // [channel][pixel], +1 pad
    int b = blockIdx.z, ct = blockIdx.y, pt = blockIdx.x;
    int p0 = pt*64, c0 = ct*64;
    int tp = threadIdx.x & 63, tc = threadIdx.x >> 6;
    const float* xb = x + ((size_t)b*C_ + c0) * HW_ + p0;
    #pragma unroll
    for (int j = 0; j < 16; ++j) {
        int cl = tc + j*4;
        float v = xb[(size_t)cl*HW_ + tp];
        tile[cl][tp] = __float2bfloat16(v);
        float s = v;
        #pragma unroll
        for (int off = 32; off; off >>= 1) s += __shfl_xor(s, off, 64);
        if (tp == 0) atomicAdd(&gap[b*C_ + c0 + cl], s);
    }
    __syncthreads();
    #pragma unroll
    for (int it = 0; it < 2; ++it) {
        int idx = it*256 + threadIdx.x;
        int px = idx >> 3, ck = idx & 7;
        bf8pack pk;
        #pragma unroll
        for (int j = 0; j < 8; ++j) pk.h[j] = tile[ck*8 + j][px];
        int c = c0 + ck*8;
        size_t dst = (((size_t)b*8 + (c >> 5))*HW_ + p0 + px)*32 + (c & 31);
        *(v8s*)(xg + dst) = pk.v;
    }
}

// ---------------------------------------------------------------------------
// 2) Gate softmax + combined bias, fused. One wave per sample. gap holds SUMS.
__global__ void alpha_kernel(const float* __restrict__ gap,
                             const float* __restrict__ gate_w,
                             const float* __restrict__ gate_b,
                             const float* __restrict__ bias,
                             float* __restrict__ alpha,
                             float* __restrict__ biasc) {
    int b = blockIdx.x, lane = threadIdx.x;
    const float inv = 1.0f / HW_;
    float g0 = gap[b*C_ + lane]*inv,       g1 = gap[b*C_ + 64 + lane]*inv;
    float g2 = gap[b*C_ + 128 + lane]*inv, g3 = gap[b*C_ + 192 + lane]*inv;
    float logit[M_];
    #pragma unroll
    for (int m = 0; m < M_; ++m) {
        const float* w = gate_w + m*C_;
        float s = g0*w[lane] + g1*w[64+lane] + g2*w[128+lane] + g3*w[192+lane];
        for (int off = 32; off; off >>= 1) s += __shfl_xor(s, off, 64);
        logit[m] = s + gate_b[m];
    }
    float mx = logit[0];
    #pragma unroll
    for (int m = 1; m < M_; ++m) mx = fmaxf(mx, logit[m]);
    float den = 0.f, e[M_];
    #pragma unroll
    for (int m = 0; m < M_; ++m) { e[m] = __expf(logit[m] - mx); den += e[m]; }
    float am[M_];
    #pragma unroll
    for (int m = 0; m < M_; ++m) am[m] = e[m] / den;
    if (lane < M_) alpha[b*M_ + lane] = am[lane];
    #pragma unroll
    for (int r = 0; r < 4; ++r) {
        int o = r*64 + lane;
        float s = 0.f;
        #pragma unroll
        for (int m = 0; m < M_; ++m) s += am[m] * bias[m*OC_ + o];
        biasc[b*OC_ + o] = s;
    }
}

// ---------------------------------------------------------------------------
// 3) Combine expert kernels: wl[b][ib(8)][tap(9)][o(256)][i_in(32)] bf16.
//    (reverted to the 288-block form: round-7's grid.y=8 split cost ~+56us
//    via 8x weight re-fetch; rest-of-pipeline time was 256us without it)
__global__ __launch_bounds__(256) void combine_kernel(const float* __restrict__ weight,
                                                      const float* __restrict__ alpha,
                                                      short* __restrict__ wl) {
    __shared__ float as[B_*M_];
    as[threadIdx.x] = alpha[threadIdx.x];
    __syncthreads();
    int gc  = blockIdx.x*256 + threadIdx.x;   // [0, 73728)
    int i8  = gc & 3;
    int o   = (gc >> 2) & 255;
    int t2  = gc >> 10;
    int tap = t2 % 9;
    int ib  = t2 / 9;
    int base = o*2304 + (ib*32 + i8*8)*9 + tap;   // + j*9
    float wv[M_][8];
    #pragma unroll
    for (int m = 0; m < M_; ++m)
        #pragma unroll
        for (int j = 0; j < 8; ++j)
            wv[m][j] = weight[(size_t)m*589824 + base + j*9];
    for (int b = 0; b < B_; ++b) {
        bf8pack pk;
        #pragma unroll
        for (int j = 0; j < 8; ++j) {
            float s = 0.f;
            #pragma unroll
            for (int m = 0; m < M_; ++m) s += as[b*M_+m] * wv[m][j];
            pk.h[j] = __float2bfloat16(s);
        }
        *(v8s*)(wl + (size_t)b*KPB_ + (size_t)gc*8) = pk.v;
    }
}

// ---------------------------------------------------------------------------
// 4) Implicit-GEMM conv, MFMA bf16 16x16x32.
//    Round-7 schedule (B-fragment register double-buffer, predicated-address
//    masking, per-ib barrier) with the register budget FIXED (round-7 spilled
//    ~2 regs -> 227/112 MB scratch traffic):
//      - areg 3 -> 2 slots (-16 regs). Distance-1 A-prefetch is now covered:
//        reg-dbuf makes the per-wave tap ~400-700 cyc; wl is 80-85% L2-hit
//        (~200 cyc).
//      - vmask[7] -> ONE packed u64 (-5 regs), compile-time bit extracts.
//    Budget: 112 acc(AGPR) + 56 brA/brB + 32 areg + 2 mask + ~25 misc ~= 227
//    <= 256 @ __launch_bounds__(256,2). LDS: 2x24KB B dbuf + zero slot.
//    Verification signature: WRITE_SIZE ~115 MB, FETCH ~60 MB (spill gone).
__global__ __launch_bounds__(256, 2) void conv_kernel(const short* __restrict__ xg,
                                                      const short* __restrict__ wl,
                                                      const float* __restrict__ biasc,
                                                      float* __restrict__ out) {
    __shared__ short smem[24584];  // B0@0, B1@12288, zero@24576 (shorts)
    const int ZOFF = 24576;

    // T1: XCD swizzle, 896 = 8*112 bijective. Consecutive swz share sample b.
    const int wg  = blockIdx.x;
    const int swz = (wg & 7) * 112 + (wg >> 3);
    const int b   = swz / 28;
    const int rm  = swz - b * 28;
    const int ot  = rm / 14;
    const int pt  = rm - ot * 14;

    const int tid = threadIdx.x;
    const int wave = tid >> 6, lane = tid & 63, q = lane >> 4, ln = lane & 15;
    const int o_half = wave >> 1, p_half = wave & 1;
    const int P0 = pt * 224;

    const int DOFF[9] = {-57,-56,-55,-1,0,1,55,56,57};

    // pad mask packed: bit (c*9 + tap), c<7, tap<9 -> 63 bits in one u64
    unsigned long long mpack = 0ull;
    #pragma unroll
    for (int c = 0; c < 7; ++c) {
        int p = P0 + p_half*112 + c*16 + ln;     // always < 3136 (14*224 exact)
        int h = p/56, w = p%56;
        #pragma unroll
        for (int tap = 0; tap < 9; ++tap) {
            int h2 = h + tap/3 - 1, w2 = w + tap%3 - 1;
            if ((unsigned)h2 < 56u && (unsigned)w2 < 56u)
                mpack |= 1ull << (c*9 + tap);
        }
    }

    const short* wbase = wl + (size_t)b*KPB_ + ((ot*128 + o_half*64 + ln)*32 + q*8);
    const short* xbase = xg + (size_t)(b*8)*HW_*32;

    auto stageB = [&](int ib, int buf) {   // 24KB halo [P0-64, P0+320), 6 gll16
        const short* src = xbase + ((long)ib*HW_ + P0 - 64)*32 + tid*8;
        short* dst = &smem[buf*12288 + tid*8];
        #pragma unroll
        for (int r = 0; r < 6; ++r) gll16(src + r*2048, dst + r*2048);
    };

    v8s areg[2][4];                        // 2 slots, distance-1 prefetch
    auto loadA = [&](int kidx, v8s (&dst)[4]) {
        const short* src = wbase + (size_t)kidx*8192;
        #pragma unroll
        for (int r = 0; r < 4; ++r) dst[r] = *(const v8s*)(src + r*512);
    };

    const int bcol0 = (64 + p_half*112 + ln)*32 + q*8;
    // predicated-address B fragment load: masked lanes read the zero slot
    auto loadBfrags = [&](int tap, int ibpar, v8s (&dst)[7]) {
        const int base = ibpar*12288 + bcol0 + DOFF[tap]*32;
        #pragma unroll
        for (int c = 0; c < 7; ++c) {
            unsigned bit = (unsigned)(mpack >> (c*9 + tap)) & 1u;
            int off = bit ? (base + c*512) : ZOFF;
            dst[c] = *(const v8s*)&smem[off];
        }
    };

    f32x4 acc[4][7];
    #pragma unroll
    for (int r = 0; r < 4; ++r)
        #pragma unroll
        for (int c = 0; c < 7; ++c) acc[r][c] = (f32x4){0.f,0.f,0.f,0.f};

    if (tid == 0) { *(v8s*)&smem[ZOFF] = (v8s){}; }   // zero slot

    // Prologue: B(0) + A k=0 (slot 0).
    stageB(0, 0);
    loadA(0, areg[0]);

    v8s brA[7], brB[7];                    // named B reg buffers (rule #20)

    for (int io = 0; io < 2; ++io) {
        #pragma unroll
        for (int i4 = 0; i4 < 4; ++i4) {
            const int ib = io*4 + i4;      // ib&1 == i4&1; (ib*9+tap)&1 == (i4+tap)&1
            // One barrier per ib: publishes B(ib), frees the other buffer.
            __syncthreads();
            if (ib < 7) stageB(ib + 1, (i4 + 1) & 1);
            loadBfrags(0, i4 & 1, brA);    // tap-0 frags (small bubble)

            #pragma unroll
            for (int tap = 0; tap < 9; ++tap) {
                const int k = ib*9 + tap;
                // prefetch next tap's B frags into the other reg buffer
                if (tap < 8) {
                    if (tap & 1) loadBfrags(tap + 1, i4 & 1, brA);
                    else         loadBfrags(tap + 1, i4 & 1, brB);
                }
                if (k + 1 < 72) loadA(k + 1, areg[(i4 + tap + 1) & 1]);

                const v8s* A  = areg[(i4 + tap) & 1];
                const v8s* Bf = (tap & 1) ? brB : brA;
                #pragma unroll
                for (int c = 0; c < 7; ++c) {
                    #pragma unroll
                    for (int r = 0; r < 4; ++r)
                        acc[r][c] = __builtin_amdgcn_mfma_f32_16x16x32_bf16(A[r], Bf[c], acc[r][c], 0, 0, 0);
                }
            }
        }
    }

    // Epilogue: D col=lane&15 (px), row=q*4+reg (o). Exact tiling, no checks.
    const int o0 = ot*128 + o_half*64 + q*4;
    #pragma unroll
    for (int c = 0; c < 7; ++c) {
        int p = P0 + p_half*112 + c*16 + ln;
        float* op = out + (size_t)b * OC_ * HW_ + p;
        #pragma unroll
        for (int r = 0; r < 4; ++r) {
            #pragma unroll
            for (int reg = 0; reg < 4; ++reg) {
                int o = o0 + r*16 + reg;
                op[(size_t)o * HW_] = acc[r][c][reg] + biasc[b*OC_ + o];
            }
        }
    }
}

// ---------------------------------------------------------------------------
extern "C" void kernel_launch(void* const* d_in, const int* in_sizes, int n_in,
                              void* d_out, int out_size, void* d_ws, size_t ws_size,
                              hipStream_t stream) {
    const float* x      = (const float*)d_in[0];
    const float* weight = (const float*)d_in[1];
    const float* bias   = (const float*)d_in[2];
    const float* gate_w = (const float*)d_in[3];
    const float* gate_b = (const float*)d_in[4];
    float* out = (float*)d_out;

    // Workspace layout (bytes):
    //   gap   @ 0       : 32,768
    //   biasc @ 32768   : 32,768
    //   alpha @ 65536   : 1,024
    //   (pad — absorbs conv's B-halo negative overrun, up to -4 KB at P0=0)
    //   xg    @ 131072  : 32*8*3136*32*2 = 51,380,224
    //   wl    @ 51,511,296 : 32*589824*2 = 37,748,736 (absorbs B-halo tail overrun)
    char* ws = (char*)d_ws;
    float* gap   = (float*)(ws);
    float* biasc = (float*)(ws + 32768);
    float* alpha = (float*)(ws + 65536);
    short* xg    = (short*)(ws + 131072);
    short* wl    = (short*)(ws + 51511296);

    zero_gap_kernel<<<32, 256, 0, stream>>>(gap);
    xcast_kernel   <<<dim3(49, 4, 32), 256, 0, stream>>>(x, xg, gap);
    alpha_kernel   <<<32,  64, 0, stream>>>(gap, gate_w, gate_b, bias, alpha, biasc);
    combine_kernel <<<288, 256, 0, stream>>>(weight, alpha, wl);
    conv_kernel    <<<896, 256, 0, stream>>>(xg, wl, biasc, out);
}